// Round 17
// baseline (352.172 us; speedup 1.0000x reference)
//
#include <hip/hip_runtime.h>
#include <hip/hip_bf16.h>
#include <math.h>

#define N_NODES 50000
#define N_EDGES 800000
#define IN_DIM 128
#define NEG_SLOPE 0.2f
// HEADS*HID = HEADS*OUT = 256 columns in both GEMMs

typedef __attribute__((ext_vector_type(8))) short s16x8;
typedef __attribute__((ext_vector_type(4))) float f32x4;

__device__ inline unsigned short f2bf(float v) {   // RNE fp32->bf16
    unsigned u = __float_as_uint(v);
    unsigned r = (u + 0x7fffu + ((u >> 16) & 1u)) >> 16;
    return (unsigned short)r;
}
__device__ inline float bf2f(unsigned short b) {
    return __uint_as_float(((unsigned)b) << 16);
}
__device__ inline float lrelu(float v) {
    return v >= 0.f ? v : NEG_SLOPE * v;
}

// ---------------- CSR build ----------------

__global__ void zero_int(int* __restrict__ p, int n) {
    int i = blockIdx.x * blockDim.x + threadIdx.x;
    if (i < n) p[i] = 0;
}

__global__ void hist_kernel(const int* __restrict__ dst, int* __restrict__ cnt) {
    int e = blockIdx.x * blockDim.x + threadIdx.x;
    if (e < N_EDGES) atomicAdd(&cnt[dst[e]], 1);
}

// parallel scan, 3 phases. phase 1: per-block (256) exclusive scan + block sums
__global__ __launch_bounds__(256) void scan_part(const int* __restrict__ cnt,
                                                 int* __restrict__ off,
                                                 int* __restrict__ part, int n) {
    __shared__ int wsum[4];
    int t = threadIdx.x, wid = t >> 6, lane = t & 63;
    int i = blockIdx.x * 256 + t;
    int v = (i < n) ? cnt[i] : 0;
    int x = v;
#pragma unroll
    for (int s = 1; s < 64; s <<= 1) {
        int u = __shfl_up(x, s, 64);
        if (lane >= s) x += u;
    }
    if (lane == 63) wsum[wid] = x;
    __syncthreads();
    if (t < 4) {
        int w = wsum[t];
#pragma unroll
        for (int s = 1; s < 4; s <<= 1) {
            int u = __shfl_up(w, s, 64);
            if (t >= s) w += u;
        }
        wsum[t] = w;
    }
    __syncthreads();
    int woff = (wid > 0) ? wsum[wid - 1] : 0;
    int incl = woff + x;
    if (i < n) off[i] = incl - v;          // block-local exclusive
    if (t == 255) part[blockIdx.x] = incl; // block total
}

// phase 2: single block scans the block totals into exclusive carries
__global__ __launch_bounds__(256) void scan_carry(int* __restrict__ part, int nb) {
    __shared__ int wsum[4];
    int t = threadIdx.x, wid = t >> 6, lane = t & 63;
    int v = (t < nb) ? part[t] : 0;
    int x = v;
#pragma unroll
    for (int s = 1; s < 64; s <<= 1) {
        int u = __shfl_up(x, s, 64);
        if (lane >= s) x += u;
    }
    if (lane == 63) wsum[wid] = x;
    __syncthreads();
    if (t < 4) {
        int w = wsum[t];
#pragma unroll
        for (int s = 1; s < 4; s <<= 1) {
            int u = __shfl_up(w, s, 64);
            if (t >= s) w += u;
        }
        wsum[t] = w;
    }
    __syncthreads();
    int woff = (wid > 0) ? wsum[wid - 1] : 0;
    if (t < nb) part[t] = woff + x - v;    // exclusive carry
}

// phase 3: add carries; also writes cur (scatter cursor) and off[n]
__global__ void scan_add(int* __restrict__ off, const int* __restrict__ part,
                         int* __restrict__ cur, int n) {
    int i = blockIdx.x * blockDim.x + threadIdx.x;
    if (i < n) {
        int val = off[i] + part[i >> 8];
        off[i] = val;
        cur[i] = val;
    }
    if (i == 0) off[n] = N_EDGES;
}

__global__ void scatter_kernel(const int* __restrict__ src, const int* __restrict__ dst,
                               int* __restrict__ cur, int* __restrict__ csr_src) {
    int e = blockIdx.x * blockDim.x + threadIdx.x;
    if (e < N_EDGES) {
        int d = dst[e];
        int pos = atomicAdd(&cur[d], 1);
        csr_src[pos] = src[e];
    }
}

// ---------------- weight prep ----------------

// W [K x 256] fp32 -> Bt hi/lo [256 x K] bf16, PERMUTED row order:
// actual col c = h*64 + rr*4 + ni stored at tile-row h*64 + ni*16 + rr,
// so a lane's 4 ni-accumulators are 4 contiguous output columns.
template <int K>
__global__ void split_wt(const float* __restrict__ W, unsigned short* __restrict__ Bth,
                         unsigned short* __restrict__ Btl) {
    int k = blockIdx.x;        // 0..K-1
    int c = threadIdx.x;       // actual output col 0..255
    int h = c >> 6, w = c & 63;
    int row = h * 64 + (w & 3) * 16 + (w >> 2);
    float v = W[(size_t)k * 256 + c];
    unsigned short hh = f2bf(v);
    Bth[(size_t)row * K + k] = hh;
    Btl[(size_t)row * K + k] = f2bf(v - bf2f(hh));
}

// wl[h] = W[:,h-strip]@al[h], wr[h] = W[:,h-strip]@ar[h]; COMPACT layout
// EhC/ElC [4 heads][2 rows][K]: row0 = wl, row1 = wr. Tiny (2-4KB) -> L1-hot.
template <int K>
__global__ void wlr_kernel(const float* __restrict__ W, const float* __restrict__ al,
                           const float* __restrict__ ar,
                           unsigned short* __restrict__ EhC, unsigned short* __restrict__ ElC) {
    int k = blockIdx.x * blockDim.x + threadIdx.x;
    if (k >= K) return;
#pragma unroll
    for (int h = 0; h < 4; h++) {
        float sl = 0.f, sr = 0.f;
        for (int c = 0; c < 64; c++) {
            float w = W[(size_t)k * 256 + h * 64 + c];
            sl += w * al[h * 64 + c];
            sr += w * ar[h * 64 + c];
        }
        unsigned short hh = f2bf(sl);
        EhC[(size_t)(h * 2 + 0) * K + k] = hh;
        ElC[(size_t)(h * 2 + 0) * K + k] = f2bf(sl - bf2f(hh));
        hh = f2bf(sr);
        EhC[(size_t)(h * 2 + 1) * K + k] = hh;
        ElC[(size_t)(h * 2 + 1) * K + k] = f2bf(sr - bf2f(hh));
    }
}

// ------- LDS-DMA MFMA GEMM, BM=128 x BN=256, 512 threads (8 waves) -------
// AF32: A staged as raw fp32 (fuses split_feat), converted to hi/lo after the
// LDS read. Otherwise A staged as precomputed bf16 hi/lo.
// LDS per buffer (49152 B):
//   AF32: A_f32 @0 [slot(fgrp*128+row)][16B] (16KB)
//   bf16: A_hi @0, A_lo @8192 [kc][128row][16B]
//   both: B_hi @16384, B_lo @32768 [kc][256row][16B]
// Wave w: head h = w&3 (64-col strip), row-half r2 = w>>2. mi=4 x ni=4 frags.
// frag: lane l holds row (l&15), k=(l>>4)*8+0..7. C/D: col=lane&15,
// row=(lane>>4)*4+reg (m89). B rows column-permuted (split_wt) -> ushort4 C store.
// e-frags direct from compact global array. el/er via e-tile MFMA, no shuffles.

#define GLDS(gsrc, loff)                                                        \
    __builtin_amdgcn_global_load_lds(                                           \
        (const __attribute__((address_space(1))) unsigned int*)(gsrc),          \
        (__attribute__((address_space(3))) unsigned int*)(lds + (loff)),        \
        16, 0, 0)

template <int K, bool AF32>
__global__ __launch_bounds__(512) void mfma_gemm(const void* __restrict__ A_,
                                                 const unsigned short* __restrict__ Alo,
                                                 const unsigned short* __restrict__ Bth,
                                                 const unsigned short* __restrict__ Btl,
                                                 const unsigned short* __restrict__ EhC,
                                                 const unsigned short* __restrict__ ElC,
                                                 unsigned short* __restrict__ Chi,
                                                 float* __restrict__ el,
                                                 float* __restrict__ er,
                                                 int M) {
    __shared__ __align__(16) char lds[98304];
    int tid = threadIdx.x;
    int w = tid >> 6;
    int h = w & 3;            // head / 64-col strip
    int r2 = w >> 2;          // row half (0/1)
    int lane = tid & 63;
    int rr = lane & 15;
    int g = lane >> 4;
    int row0 = blockIdx.x * 128;

    // staging source addresses (fixed across k-steps)
    int arow = row0 + (tid & 127);
    if (arow >= M) arow = M - 1;
    const float* Af = (const float*)A_;
    const unsigned short* Ah = (const unsigned short*)A_;
    int fg = (tid >> 7) & 3;                  // AF32: float4 group 0..3 (d0), +4 (d1)
    const float* afsrc0 = Af + (size_t)arow * K + fg * 4;
    const float* afsrc1 = Af + (size_t)arow * K + (fg + 4) * 4;
    int akc = (tid >> 7) & 3;                 // bf16: kc 0..3
    const unsigned short* asrc_h = Ah + (size_t)arow * K + akc * 8;
    const unsigned short* asrc_l = Alo + (size_t)arow * K + akc * 8;
    int btrow = tid & 255;
    int bkc = (tid >> 8) * 2;                 // 0 or 2
    const unsigned short* bsrc_h = Bth + (size_t)btrow * K + bkc * 8;
    const unsigned short* bsrc_l = Btl + (size_t)btrow * K + bkc * 8;
    int bdst0 = 16384 + bkc * 4096 + btrow * 16;
    int bdst1 = 16384 + (bkc + 1) * 4096 + btrow * 16;

    f32x4 acc[4][4] = {};
    f32x4 acce[4] = {};

    // prologue: stage k-step 0 into buffer 0  (6 DMA/thread)
    if (AF32) {
        GLDS(afsrc0, tid * 16);
        GLDS(afsrc1, 8192 + tid * 16);
    } else {
        GLDS(asrc_h, tid * 16);
        GLDS(asrc_l, 8192 + tid * 16);
    }
    GLDS(bsrc_h, bdst0);
    GLDS(bsrc_h + 8, bdst1);
    GLDS(bsrc_l, 16384 + bdst0);
    GLDS(bsrc_l + 8, 16384 + bdst1);

    int cur = 0;
    for (int kb = 0; kb < K; kb += 32) {
        __syncthreads();                      // staging of buf(cur) complete
        if (kb + 32 < K) {
            int nb = (cur ^ 1) * 49152;
            if (AF32) {
                GLDS(afsrc0 + kb + 32, nb + tid * 16);
                GLDS(afsrc1 + kb + 32, nb + 8192 + tid * 16);
            } else {
                GLDS(asrc_h + kb + 32, nb + tid * 16);
                GLDS(asrc_l + kb + 32, nb + 8192 + tid * 16);
            }
            GLDS(bsrc_h + kb + 32, nb + bdst0);
            GLDS(bsrc_h + kb + 40, nb + bdst1);
            GLDS(bsrc_l + kb + 32, nb + 16384 + bdst0);
            GLDS(bsrc_l + kb + 40, nb + 16384 + bdst1);
        }
        // e-frags direct from tiny global array (L1-hot; only lanes rr<2 load)
        s16x8 ehf = {};
        s16x8 elf = {};
        if (rr < 2) {
            ehf = *reinterpret_cast<const s16x8*>(EhC + (size_t)(h * 2 + rr) * K + kb + g * 8);
            elf = *reinterpret_cast<const s16x8*>(ElC + (size_t)(h * 2 + rr) * K + kb + g * 8);
        }
        const char* lb = lds + cur * 49152;
        s16x8 ah[4], al[4], bh[4], bl[4];
#pragma unroll
        for (int mi = 0; mi < 4; mi++) {
            int row = r2 * 64 + mi * 16 + rr;
            if (AF32) {
                float4 f0 = *reinterpret_cast<const float4*>(lb + g * 4096 + row * 16);
                float4 f1 = *reinterpret_cast<const float4*>(lb + g * 4096 + 2048 + row * 16);
                float vv[8] = {f0.x, f0.y, f0.z, f0.w, f1.x, f1.y, f1.z, f1.w};
#pragma unroll
                for (int i = 0; i < 8; i++) {
                    unsigned short hh = f2bf(vv[i]);
                    ah[mi][i] = (short)hh;
                    al[mi][i] = (short)f2bf(vv[i] - bf2f(hh));
                }
            } else {
                int off = g * 2048 + row * 16;
                ah[mi] = *reinterpret_cast<const s16x8*>(lb + off);
                al[mi] = *reinterpret_cast<const s16x8*>(lb + 8192 + off);
            }
        }
#pragma unroll
        for (int ni = 0; ni < 4; ni++) {
            int off = g * 4096 + (h * 64 + ni * 16 + rr) * 16;
            bh[ni] = *reinterpret_cast<const s16x8*>(lb + 16384 + off);
            bl[ni] = *reinterpret_cast<const s16x8*>(lb + 32768 + off);
        }
#pragma unroll
        for (int mi = 0; mi < 4; mi++) {
#pragma unroll
            for (int ni = 0; ni < 4; ni++) {
                acc[mi][ni] = __builtin_amdgcn_mfma_f32_16x16x32_bf16(ah[mi], bh[ni], acc[mi][ni], 0, 0, 0);
                acc[mi][ni] = __builtin_amdgcn_mfma_f32_16x16x32_bf16(ah[mi], bl[ni], acc[mi][ni], 0, 0, 0);
                acc[mi][ni] = __builtin_amdgcn_mfma_f32_16x16x32_bf16(al[mi], bh[ni], acc[mi][ni], 0, 0, 0);
            }
            acce[mi] = __builtin_amdgcn_mfma_f32_16x16x32_bf16(ah[mi], ehf, acce[mi], 0, 0, 0);
            acce[mi] = __builtin_amdgcn_mfma_f32_16x16x32_bf16(ah[mi], elf, acce[mi], 0, 0, 0);
            acce[mi] = __builtin_amdgcn_mfma_f32_16x16x32_bf16(al[mi], ehf, acce[mi], 0, 0, 0);
        }
        cur ^= 1;
    }

    // epilogue: contiguous ushort4 C store + direct el/er store (no shuffles)
#pragma unroll
    for (int mi = 0; mi < 4; mi++) {
#pragma unroll
        for (int reg = 0; reg < 4; reg++) {
            int row = row0 + r2 * 64 + mi * 16 + g * 4 + reg;
            if (row < M) {
                ushort4 u;
                u.x = f2bf(acc[mi][0][reg]);
                u.y = f2bf(acc[mi][1][reg]);
                u.z = f2bf(acc[mi][2][reg]);
                u.w = f2bf(acc[mi][3][reg]);
                *reinterpret_cast<ushort4*>(&Chi[(size_t)row * 256 + h * 64 + rr * 4]) = u;
                if (rr == 0) el[row * 4 + h] = acce[mi][reg];
                if (rr == 1) er[row * 4 + h] = acce[mi][reg];
            }
        }
    }
}

// ------- aggregation: one wave per node, 8 INDEPENDENT waves per block -------
// 512-thread blocks, no LDS, no barriers: wave w handles node blk*8+w alone.
// (r16 had 4-wave blocks at 50% occupancy; this probes the blocks/CU cap.)
// lane l holds features l*4..l*4+3; head h = l>>4. batch-8 online softmax.

template <int LAYER>
__global__ __launch_bounds__(512) void agg_kernel(const unsigned short* __restrict__ feat16,
                                                  const float* __restrict__ el,
                                                  const float* __restrict__ er,
                                                  const int* __restrict__ row_off,
                                                  const int* __restrict__ csr_src,
                                                  const float* __restrict__ bias,
                                                  unsigned short* __restrict__ out_hi,
                                                  unsigned short* __restrict__ out_lo,
                                                  float* __restrict__ outf) {
    int n = blockIdx.x * 8 + (threadIdx.x >> 6);   // 6250 blocks * 8 waves = 50000
    int lane = threadIdx.x & 63;
    int h = lane >> 4;
    int js = row_off[n], je = row_off[n + 1];
    float er_nh = er[n * 4 + h];
    float m = -INFINITY, ssum = 0.f;
    float4 acc = make_float4(0.f, 0.f, 0.f, 0.f);
    int j = js;
    for (; j + 7 < je; j += 8) {
        int ss[8]; ushort4 uu[8]; float vv[8];
#pragma unroll
        for (int q = 0; q < 8; q++) ss[q] = csr_src[j + q];
#pragma unroll
        for (int q = 0; q < 8; q++)
            uu[q] = *reinterpret_cast<const ushort4*>(&feat16[(size_t)ss[q] * 256 + lane * 4]);
#pragma unroll
        for (int q = 0; q < 8; q++) vv[q] = lrelu(el[ss[q] * 4 + h] + er_nh);
        float mx = fmaxf(fmaxf(fmaxf(vv[0], vv[1]), fmaxf(vv[2], vv[3])),
                         fmaxf(fmaxf(vv[4], vv[5]), fmaxf(vv[6], vv[7])));
        float mn = fmaxf(m, mx);
        float sc = __expf(m - mn);     // 0 when m == -inf
        float p[8];
#pragma unroll
        for (int q = 0; q < 8; q++) p[q] = __expf(vv[q] - mn);
        float psum = ((p[0] + p[1]) + (p[2] + p[3])) + ((p[4] + p[5]) + (p[6] + p[7]));
        ssum = ssum * sc + psum;
        float ax = 0.f, ay = 0.f, az = 0.f, aw = 0.f;
#pragma unroll
        for (int q = 0; q < 8; q++) {
            ax += p[q] * bf2f(uu[q].x);
            ay += p[q] * bf2f(uu[q].y);
            az += p[q] * bf2f(uu[q].z);
            aw += p[q] * bf2f(uu[q].w);
        }
        acc.x = acc.x * sc + ax;
        acc.y = acc.y * sc + ay;
        acc.z = acc.z * sc + az;
        acc.w = acc.w * sc + aw;
        m = mn;
    }
    for (; j + 3 < je; j += 4) {
        int s0 = csr_src[j], s1 = csr_src[j + 1], s2 = csr_src[j + 2], s3 = csr_src[j + 3];
        ushort4 u0 = *reinterpret_cast<const ushort4*>(&feat16[(size_t)s0 * 256 + lane * 4]);
        ushort4 u1 = *reinterpret_cast<const ushort4*>(&feat16[(size_t)s1 * 256 + lane * 4]);
        ushort4 u2 = *reinterpret_cast<const ushort4*>(&feat16[(size_t)s2 * 256 + lane * 4]);
        ushort4 u3 = *reinterpret_cast<const ushort4*>(&feat16[(size_t)s3 * 256 + lane * 4]);
        float v0 = lrelu(el[s0 * 4 + h] + er_nh);
        float v1 = lrelu(el[s1 * 4 + h] + er_nh);
        float v2 = lrelu(el[s2 * 4 + h] + er_nh);
        float v3 = lrelu(el[s3 * 4 + h] + er_nh);
        float mx = fmaxf(fmaxf(v0, v1), fmaxf(v2, v3));
        float mn = fmaxf(m, mx);
        float sc = __expf(m - mn);
        float p0 = __expf(v0 - mn);
        float p1 = __expf(v1 - mn);
        float p2 = __expf(v2 - mn);
        float p3 = __expf(v3 - mn);
        ssum = ssum * sc + ((p0 + p1) + (p2 + p3));
        acc.x = acc.x * sc + (p0 * bf2f(u0.x) + p1 * bf2f(u1.x)) + (p2 * bf2f(u2.x) + p3 * bf2f(u3.x));
        acc.y = acc.y * sc + (p0 * bf2f(u0.y) + p1 * bf2f(u1.y)) + (p2 * bf2f(u2.y) + p3 * bf2f(u3.y));
        acc.z = acc.z * sc + (p0 * bf2f(u0.z) + p1 * bf2f(u1.z)) + (p2 * bf2f(u2.z) + p3 * bf2f(u3.z));
        acc.w = acc.w * sc + (p0 * bf2f(u0.w) + p1 * bf2f(u1.w)) + (p2 * bf2f(u2.w) + p3 * bf2f(u3.w));
        m = mn;
    }
    for (; j < je; j++) {
        int s = csr_src[j];
        ushort4 u = *reinterpret_cast<const ushort4*>(&feat16[(size_t)s * 256 + lane * 4]);
        float val = lrelu(el[s * 4 + h] + er_nh);
        float mn = fmaxf(m, val);
        float sc = __expf(m - mn);
        float p = __expf(val - mn);
        ssum = ssum * sc + p;
        acc.x = acc.x * sc + p * bf2f(u.x);
        acc.y = acc.y * sc + p * bf2f(u.y);
        acc.z = acc.z * sc + p * bf2f(u.z);
        acc.w = acc.w * sc + p * bf2f(u.w);
        m = mn;
    }
    float inv = 1.f / fmaxf(ssum, 1e-9f);
    // bias index: h*64 + (lane&15)*4 + i == lane*4 + i
    float4 res;
    res.x = acc.x * inv + bias[lane * 4 + 0];
    res.y = acc.y * inv + bias[lane * 4 + 1];
    res.z = acc.z * inv + bias[lane * 4 + 2];
    res.w = acc.w * inv + bias[lane * 4 + 3];
    if (LAYER == 1) {
        res.x = res.x > 0.f ? res.x : __expf(res.x) - 1.f;
        res.y = res.y > 0.f ? res.y : __expf(res.y) - 1.f;
        res.z = res.z > 0.f ? res.z : __expf(res.z) - 1.f;
        res.w = res.w > 0.f ? res.w : __expf(res.w) - 1.f;
        ushort4 hz, lz;
        hz.x = f2bf(res.x); lz.x = f2bf(res.x - bf2f(hz.x));
        hz.y = f2bf(res.y); lz.y = f2bf(res.y - bf2f(hz.y));
        hz.z = f2bf(res.z); lz.z = f2bf(res.z - bf2f(hz.z));
        hz.w = f2bf(res.w); lz.w = f2bf(res.w - bf2f(hz.w));
        *reinterpret_cast<ushort4*>(&out_hi[(size_t)n * 256 + lane * 4]) = hz;
        *reinterpret_cast<ushort4*>(&out_lo[(size_t)n * 256 + lane * 4]) = lz;
    } else {
        // mean over heads: feature f held by lanes {f>>2, +16, +32, +48}
#pragma unroll
        for (int mask = 16; mask <= 32; mask <<= 1) {
            res.x += __shfl_xor(res.x, mask, 64);
            res.y += __shfl_xor(res.y, mask, 64);
            res.z += __shfl_xor(res.z, mask, 64);
            res.w += __shfl_xor(res.w, mask, 64);
        }
        if (lane < 16) {
            float4 o = make_float4(res.x * 0.25f, res.y * 0.25f, res.z * 0.25f, res.w * 0.25f);
            *reinterpret_cast<float4*>(&outf[(size_t)n * 64 + lane * 4]) = o;
        }
    }
}

// ---------------- launch ----------------

extern "C" void kernel_launch(void* const* d_in, const int* in_sizes, int n_in,
                              void* d_out, int out_size, void* d_ws, size_t ws_size,
                              hipStream_t stream) {
    const float* features = (const float*)d_in[0];
    const int*   src      = (const int*)d_in[1];
    const int*   dst      = (const int*)d_in[2];
    const float* W1       = (const float*)d_in[3];
    const float* al1      = (const float*)d_in[4];
    const float* ar1      = (const float*)d_in[5];
    const float* b1       = (const float*)d_in[6];
    const float* W2       = (const float*)d_in[7];
    const float* al2      = (const float*)d_in[8];
    const float* ar2      = (const float*)d_in[9];
    const float* b2       = (const float*)d_in[10];
    float* out = (float*)d_out;

    char* ws = (char*)d_ws;
    unsigned short* feat16  = (unsigned short*)(ws);             // 25,600,000 B [50000x256]
    unsigned short* h1_hi   = (unsigned short*)(ws + 25600000);  // 25,600,000 B
    unsigned short* h1_lo   = (unsigned short*)(ws + 51200000);  // 25,600,000 B
    unsigned short* Bt1_hi  = (unsigned short*)(ws + 76800000);  //     65,536 B
    unsigned short* Bt1_lo  = (unsigned short*)(ws + 76865536);  //     65,536 B
    unsigned short* Bt2_hi  = (unsigned short*)(ws + 76931072);  //    131,072 B
    unsigned short* Bt2_lo  = (unsigned short*)(ws + 77062144);  //    131,072 B
    unsigned short* E1C_hi  = (unsigned short*)(ws + 77193216);  //      2,048 B [4][2][128]
    unsigned short* E1C_lo  = (unsigned short*)(ws + 77195264);  //      2,048 B
    unsigned short* E2C_hi  = (unsigned short*)(ws + 77197312);  //      4,096 B [4][2][256]
    unsigned short* E2C_lo  = (unsigned short*)(ws + 77201408);  //      4,096 B
    float*          el      = (float*)(ws + 77205504);           //    800,000 B
    float*          er      = (float*)(ws + 78005504);           //    800,000 B
    int*            row_off = (int*)  (ws + 78805504);           //    200,064 B
    int*            cur     = (int*)  (ws + 79005568);           //    200,000 B
    int*            part    = (int*)  (ws + 79205568);           //      1,024 B
    int*            csr     = (int*)  (ws + 79206592);           //  3,200,000 B (end ~82.4 MB)

    // --- CSR build (graph shared by both layers) ---
    zero_int<<<(N_NODES + 255) / 256, 256, 0, stream>>>(cur, N_NODES);
    hist_kernel<<<(N_EDGES + 255) / 256, 256, 0, stream>>>(dst, cur);
    int nb = (N_NODES + 255) / 256;   // 196
    scan_part<<<nb, 256, 0, stream>>>(cur, row_off, part, N_NODES);
    scan_carry<<<1, 256, 0, stream>>>(part, nb);
    scan_add<<<(N_NODES + 255) / 256, 256, 0, stream>>>(row_off, part, cur, N_NODES);
    scatter_kernel<<<(N_EDGES + 255) / 256, 256, 0, stream>>>(src, dst, cur, csr);

    // --- weight prep ---
    split_wt<IN_DIM><<<IN_DIM, 256, 0, stream>>>(W1, Bt1_hi, Bt1_lo);
    split_wt<256><<<256, 256, 0, stream>>>(W2, Bt2_hi, Bt2_lo);
    wlr_kernel<IN_DIM><<<1, IN_DIM, 0, stream>>>(W1, al1, ar1, E1C_hi, E1C_lo);
    wlr_kernel<256><<<1, 256, 0, stream>>>(W2, al2, ar2, E2C_hi, E2C_lo);

    int gemm_blocks = (N_NODES + 127) / 128;   // 391

    // --- layer 1 (A = fp32 features, split fused into staging) ---
    mfma_gemm<IN_DIM, true><<<gemm_blocks, 512, 0, stream>>>(
        features, nullptr, Bt1_hi, Bt1_lo, E1C_hi, E1C_lo, feat16, el, er, N_NODES);
    agg_kernel<1><<<6250, 512, 0, stream>>>(feat16, el, er, row_off, csr, b1, h1_hi, h1_lo, nullptr);

    // --- layer 2 (A = h1 hi/lo bf16) ---
    mfma_gemm<256, false><<<gemm_blocks, 512, 0, stream>>>(
        h1_hi, h1_lo, Bt2_hi, Bt2_lo, E2C_hi, E2C_lo, feat16, el, er, N_NODES);
    agg_kernel<2><<<6250, 512, 0, stream>>>(feat16, el, er, row_off, csr, b2, nullptr, nullptr, out);
}

// Round 18
// 343.283 us; speedup vs baseline: 1.0259x; 1.0259x over previous
//
#include <hip/hip_runtime.h>
#include <hip/hip_bf16.h>
#include <math.h>

#define N_NODES 50000
#define N_EDGES 800000
#define IN_DIM 128
#define NEG_SLOPE 0.2f
// HEADS*HID = HEADS*OUT = 256 columns in both GEMMs

typedef __attribute__((ext_vector_type(8))) short s16x8;
typedef __attribute__((ext_vector_type(4))) float f32x4;

__device__ inline unsigned short f2bf(float v) {   // RNE fp32->bf16
    unsigned u = __float_as_uint(v);
    unsigned r = (u + 0x7fffu + ((u >> 16) & 1u)) >> 16;
    return (unsigned short)r;
}
__device__ inline float bf2f(unsigned short b) {
    return __uint_as_float(((unsigned)b) << 16);
}
__device__ inline float lrelu(float v) {
    return v >= 0.f ? v : NEG_SLOPE * v;
}

// ---------------- CSR build ----------------

__global__ void zero_int(int* __restrict__ p, int n) {
    int i = blockIdx.x * blockDim.x + threadIdx.x;
    if (i < n) p[i] = 0;
}

__global__ void hist_kernel(const int* __restrict__ dst, int* __restrict__ cnt) {
    int e = blockIdx.x * blockDim.x + threadIdx.x;
    if (e < N_EDGES) atomicAdd(&cnt[dst[e]], 1);
}

// parallel scan, 3 phases. phase 1: per-block (256) exclusive scan + block sums
__global__ __launch_bounds__(256) void scan_part(const int* __restrict__ cnt,
                                                 int* __restrict__ off,
                                                 int* __restrict__ part, int n) {
    __shared__ int wsum[4];
    int t = threadIdx.x, wid = t >> 6, lane = t & 63;
    int i = blockIdx.x * 256 + t;
    int v = (i < n) ? cnt[i] : 0;
    int x = v;
#pragma unroll
    for (int s = 1; s < 64; s <<= 1) {
        int u = __shfl_up(x, s, 64);
        if (lane >= s) x += u;
    }
    if (lane == 63) wsum[wid] = x;
    __syncthreads();
    if (t < 4) {
        int w = wsum[t];
#pragma unroll
        for (int s = 1; s < 4; s <<= 1) {
            int u = __shfl_up(w, s, 64);
            if (t >= s) w += u;
        }
        wsum[t] = w;
    }
    __syncthreads();
    int woff = (wid > 0) ? wsum[wid - 1] : 0;
    int incl = woff + x;
    if (i < n) off[i] = incl - v;          // block-local exclusive
    if (t == 255) part[blockIdx.x] = incl; // block total
}

// phase 2: single block scans the block totals into exclusive carries
__global__ __launch_bounds__(256) void scan_carry(int* __restrict__ part, int nb) {
    __shared__ int wsum[4];
    int t = threadIdx.x, wid = t >> 6, lane = t & 63;
    int v = (t < nb) ? part[t] : 0;
    int x = v;
#pragma unroll
    for (int s = 1; s < 64; s <<= 1) {
        int u = __shfl_up(x, s, 64);
        if (lane >= s) x += u;
    }
    if (lane == 63) wsum[wid] = x;
    __syncthreads();
    if (t < 4) {
        int w = wsum[t];
#pragma unroll
        for (int s = 1; s < 4; s <<= 1) {
            int u = __shfl_up(w, s, 64);
            if (t >= s) w += u;
        }
        wsum[t] = w;
    }
    __syncthreads();
    int woff = (wid > 0) ? wsum[wid - 1] : 0;
    if (t < nb) part[t] = woff + x - v;    // exclusive carry
}

// phase 3: add carries; also writes cur (scatter cursor) and off[n]
__global__ void scan_add(int* __restrict__ off, const int* __restrict__ part,
                         int* __restrict__ cur, int n) {
    int i = blockIdx.x * blockDim.x + threadIdx.x;
    if (i < n) {
        int val = off[i] + part[i >> 8];
        off[i] = val;
        cur[i] = val;
    }
    if (i == 0) off[n] = N_EDGES;
}

__global__ void scatter_kernel(const int* __restrict__ src, const int* __restrict__ dst,
                               int* __restrict__ cur, int* __restrict__ csr_src) {
    int e = blockIdx.x * blockDim.x + threadIdx.x;
    if (e < N_EDGES) {
        int d = dst[e];
        int pos = atomicAdd(&cur[d], 1);
        csr_src[pos] = src[e];
    }
}

// ---------------- weight prep ----------------

// W [K x 256] fp32 -> Bt hi/lo [256 x K] bf16, PERMUTED row order:
// actual col c = h*64 + rr*4 + ni stored at tile-row h*64 + ni*16 + rr,
// so a lane's 4 ni-accumulators are 4 contiguous output columns.
template <int K>
__global__ void split_wt(const float* __restrict__ W, unsigned short* __restrict__ Bth,
                         unsigned short* __restrict__ Btl) {
    int k = blockIdx.x;        // 0..K-1
    int c = threadIdx.x;       // actual output col 0..255
    int h = c >> 6, w = c & 63;
    int row = h * 64 + (w & 3) * 16 + (w >> 2);
    float v = W[(size_t)k * 256 + c];
    unsigned short hh = f2bf(v);
    Bth[(size_t)row * K + k] = hh;
    Btl[(size_t)row * K + k] = f2bf(v - bf2f(hh));
}

// wl[h] = W[:,h-strip]@al[h], wr[h] = W[:,h-strip]@ar[h]; COMPACT layout
// EhC/ElC [4 heads][2 rows][K]: row0 = wl, row1 = wr. Tiny (2-4KB) -> L1-hot.
template <int K>
__global__ void wlr_kernel(const float* __restrict__ W, const float* __restrict__ al,
                           const float* __restrict__ ar,
                           unsigned short* __restrict__ EhC, unsigned short* __restrict__ ElC) {
    int k = blockIdx.x * blockDim.x + threadIdx.x;
    if (k >= K) return;
#pragma unroll
    for (int h = 0; h < 4; h++) {
        float sl = 0.f, sr = 0.f;
        for (int c = 0; c < 64; c++) {
            float w = W[(size_t)k * 256 + h * 64 + c];
            sl += w * al[h * 64 + c];
            sr += w * ar[h * 64 + c];
        }
        unsigned short hh = f2bf(sl);
        EhC[(size_t)(h * 2 + 0) * K + k] = hh;
        ElC[(size_t)(h * 2 + 0) * K + k] = f2bf(sl - bf2f(hh));
        hh = f2bf(sr);
        EhC[(size_t)(h * 2 + 1) * K + k] = hh;
        ElC[(size_t)(h * 2 + 1) * K + k] = f2bf(sr - bf2f(hh));
    }
}

// ------- LDS-DMA MFMA GEMM, BM=128 x BN=256, 512 threads (8 waves) -------
// AF32: A staged as raw fp32 (fuses split_feat), converted to hi/lo after the
// LDS read. Otherwise A staged as precomputed bf16 hi/lo.
// LDS per buffer (49152 B):
//   AF32: A_f32 @0 [slot(fgrp*128+row)][16B] (16KB)
//   bf16: A_hi @0, A_lo @8192 [kc][128row][16B]
//   both: B_hi @16384, B_lo @32768 [kc][256row][16B]
// Wave w: head h = w&3 (64-col strip), row-half r2 = w>>2. mi=4 x ni=4 frags.
// frag: lane l holds row (l&15), k=(l>>4)*8+0..7. C/D: col=lane&15,
// row=(lane>>4)*4+reg (m89). B rows column-permuted (split_wt) -> ushort4 C store.
// e-frags direct from compact global array. el/er via e-tile MFMA, no shuffles.

#define GLDS(gsrc, loff)                                                        \
    __builtin_amdgcn_global_load_lds(                                           \
        (const __attribute__((address_space(1))) unsigned int*)(gsrc),          \
        (__attribute__((address_space(3))) unsigned int*)(lds + (loff)),        \
        16, 0, 0)

template <int K, bool AF32>
__global__ __launch_bounds__(512) void mfma_gemm(const void* __restrict__ A_,
                                                 const unsigned short* __restrict__ Alo,
                                                 const unsigned short* __restrict__ Bth,
                                                 const unsigned short* __restrict__ Btl,
                                                 const unsigned short* __restrict__ EhC,
                                                 const unsigned short* __restrict__ ElC,
                                                 unsigned short* __restrict__ Chi,
                                                 float* __restrict__ el,
                                                 float* __restrict__ er,
                                                 int M) {
    __shared__ __align__(16) char lds[98304];
    int tid = threadIdx.x;
    int w = tid >> 6;
    int h = w & 3;            // head / 64-col strip
    int r2 = w >> 2;          // row half (0/1)
    int lane = tid & 63;
    int rr = lane & 15;
    int g = lane >> 4;
    int row0 = blockIdx.x * 128;

    // staging source addresses (fixed across k-steps)
    int arow = row0 + (tid & 127);
    if (arow >= M) arow = M - 1;
    const float* Af = (const float*)A_;
    const unsigned short* Ah = (const unsigned short*)A_;
    int fg = (tid >> 7) & 3;                  // AF32: float4 group 0..3 (d0), +4 (d1)
    const float* afsrc0 = Af + (size_t)arow * K + fg * 4;
    const float* afsrc1 = Af + (size_t)arow * K + (fg + 4) * 4;
    int akc = (tid >> 7) & 3;                 // bf16: kc 0..3
    const unsigned short* asrc_h = Ah + (size_t)arow * K + akc * 8;
    const unsigned short* asrc_l = Alo + (size_t)arow * K + akc * 8;
    int btrow = tid & 255;
    int bkc = (tid >> 8) * 2;                 // 0 or 2
    const unsigned short* bsrc_h = Bth + (size_t)btrow * K + bkc * 8;
    const unsigned short* bsrc_l = Btl + (size_t)btrow * K + bkc * 8;
    int bdst0 = 16384 + bkc * 4096 + btrow * 16;
    int bdst1 = 16384 + (bkc + 1) * 4096 + btrow * 16;

    f32x4 acc[4][4] = {};
    f32x4 acce[4] = {};

    // prologue: stage k-step 0 into buffer 0  (6 DMA/thread)
    if (AF32) {
        GLDS(afsrc0, tid * 16);
        GLDS(afsrc1, 8192 + tid * 16);
    } else {
        GLDS(asrc_h, tid * 16);
        GLDS(asrc_l, 8192 + tid * 16);
    }
    GLDS(bsrc_h, bdst0);
    GLDS(bsrc_h + 8, bdst1);
    GLDS(bsrc_l, 16384 + bdst0);
    GLDS(bsrc_l + 8, 16384 + bdst1);

    int cur = 0;
    for (int kb = 0; kb < K; kb += 32) {
        __syncthreads();                      // staging of buf(cur) complete
        if (kb + 32 < K) {
            int nb = (cur ^ 1) * 49152;
            if (AF32) {
                GLDS(afsrc0 + kb + 32, nb + tid * 16);
                GLDS(afsrc1 + kb + 32, nb + 8192 + tid * 16);
            } else {
                GLDS(asrc_h + kb + 32, nb + tid * 16);
                GLDS(asrc_l + kb + 32, nb + 8192 + tid * 16);
            }
            GLDS(bsrc_h + kb + 32, nb + bdst0);
            GLDS(bsrc_h + kb + 40, nb + bdst1);
            GLDS(bsrc_l + kb + 32, nb + 16384 + bdst0);
            GLDS(bsrc_l + kb + 40, nb + 16384 + bdst1);
        }
        // e-frags direct from tiny global array (L1-hot; only lanes rr<2 load)
        s16x8 ehf = {};
        s16x8 elf = {};
        if (rr < 2) {
            ehf = *reinterpret_cast<const s16x8*>(EhC + (size_t)(h * 2 + rr) * K + kb + g * 8);
            elf = *reinterpret_cast<const s16x8*>(ElC + (size_t)(h * 2 + rr) * K + kb + g * 8);
        }
        const char* lb = lds + cur * 49152;
        s16x8 ah[4], al[4], bh[4], bl[4];
#pragma unroll
        for (int mi = 0; mi < 4; mi++) {
            int row = r2 * 64 + mi * 16 + rr;
            if (AF32) {
                float4 f0 = *reinterpret_cast<const float4*>(lb + g * 4096 + row * 16);
                float4 f1 = *reinterpret_cast<const float4*>(lb + g * 4096 + 2048 + row * 16);
                float vv[8] = {f0.x, f0.y, f0.z, f0.w, f1.x, f1.y, f1.z, f1.w};
#pragma unroll
                for (int i = 0; i < 8; i++) {
                    unsigned short hh = f2bf(vv[i]);
                    ah[mi][i] = (short)hh;
                    al[mi][i] = (short)f2bf(vv[i] - bf2f(hh));
                }
            } else {
                int off = g * 2048 + row * 16;
                ah[mi] = *reinterpret_cast<const s16x8*>(lb + off);
                al[mi] = *reinterpret_cast<const s16x8*>(lb + 8192 + off);
            }
        }
#pragma unroll
        for (int ni = 0; ni < 4; ni++) {
            int off = g * 4096 + (h * 64 + ni * 16 + rr) * 16;
            bh[ni] = *reinterpret_cast<const s16x8*>(lb + 16384 + off);
            bl[ni] = *reinterpret_cast<const s16x8*>(lb + 32768 + off);
        }
#pragma unroll
        for (int mi = 0; mi < 4; mi++) {
#pragma unroll
            for (int ni = 0; ni < 4; ni++) {
                acc[mi][ni] = __builtin_amdgcn_mfma_f32_16x16x32_bf16(ah[mi], bh[ni], acc[mi][ni], 0, 0, 0);
                acc[mi][ni] = __builtin_amdgcn_mfma_f32_16x16x32_bf16(ah[mi], bl[ni], acc[mi][ni], 0, 0, 0);
                acc[mi][ni] = __builtin_amdgcn_mfma_f32_16x16x32_bf16(al[mi], bh[ni], acc[mi][ni], 0, 0, 0);
            }
            acce[mi] = __builtin_amdgcn_mfma_f32_16x16x32_bf16(ah[mi], ehf, acce[mi], 0, 0, 0);
            acce[mi] = __builtin_amdgcn_mfma_f32_16x16x32_bf16(ah[mi], elf, acce[mi], 0, 0, 0);
            acce[mi] = __builtin_amdgcn_mfma_f32_16x16x32_bf16(al[mi], ehf, acce[mi], 0, 0, 0);
        }
        cur ^= 1;
    }

    // epilogue: contiguous ushort4 C store + direct el/er store (no shuffles)
#pragma unroll
    for (int mi = 0; mi < 4; mi++) {
#pragma unroll
        for (int reg = 0; reg < 4; reg++) {
            int row = row0 + r2 * 64 + mi * 16 + g * 4 + reg;
            if (row < M) {
                ushort4 u;
                u.x = f2bf(acc[mi][0][reg]);
                u.y = f2bf(acc[mi][1][reg]);
                u.z = f2bf(acc[mi][2][reg]);
                u.w = f2bf(acc[mi][3][reg]);
                *reinterpret_cast<ushort4*>(&Chi[(size_t)row * 256 + h * 64 + rr * 4]) = u;
                if (rr == 0) el[row * 4 + h] = acce[mi][reg];
                if (rr == 1) er[row * 4 + h] = acce[mi][reg];
            }
        }
    }
}

// ------- aggregation: one wave per node, all 4 heads, batch-8 online softmax -------
// (r16 structure, confirmed local optimum: r15's 2-wave split AND r17's 8-wave
// blocks both regressed — 256-thread/4-wave decoupled blocks win.)
// lane l holds features l*4..l*4+3; head h = l>>4.

template <int LAYER>
__global__ __launch_bounds__(256) void agg_kernel(const unsigned short* __restrict__ feat16,
                                                  const float* __restrict__ el,
                                                  const float* __restrict__ er,
                                                  const int* __restrict__ row_off,
                                                  const int* __restrict__ csr_src,
                                                  const float* __restrict__ bias,
                                                  unsigned short* __restrict__ out_hi,
                                                  unsigned short* __restrict__ out_lo,
                                                  float* __restrict__ outf) {
    int n = blockIdx.x * 4 + (threadIdx.x >> 6);   // 12500 blocks * 4 waves = 50000
    int lane = threadIdx.x & 63;
    int h = lane >> 4;
    int js = row_off[n], je = row_off[n + 1];
    float er_nh = er[n * 4 + h];
    float m = -INFINITY, ssum = 0.f;
    float4 acc = make_float4(0.f, 0.f, 0.f, 0.f);
    int j = js;
    for (; j + 7 < je; j += 8) {
        int ss[8]; ushort4 uu[8]; float vv[8];
#pragma unroll
        for (int q = 0; q < 8; q++) ss[q] = csr_src[j + q];
#pragma unroll
        for (int q = 0; q < 8; q++)
            uu[q] = *reinterpret_cast<const ushort4*>(&feat16[(size_t)ss[q] * 256 + lane * 4]);
#pragma unroll
        for (int q = 0; q < 8; q++) vv[q] = lrelu(el[ss[q] * 4 + h] + er_nh);
        float mx = fmaxf(fmaxf(fmaxf(vv[0], vv[1]), fmaxf(vv[2], vv[3])),
                         fmaxf(fmaxf(vv[4], vv[5]), fmaxf(vv[6], vv[7])));
        float mn = fmaxf(m, mx);
        float sc = __expf(m - mn);     // 0 when m == -inf
        float p[8];
#pragma unroll
        for (int q = 0; q < 8; q++) p[q] = __expf(vv[q] - mn);
        float psum = ((p[0] + p[1]) + (p[2] + p[3])) + ((p[4] + p[5]) + (p[6] + p[7]));
        ssum = ssum * sc + psum;
        float ax = 0.f, ay = 0.f, az = 0.f, aw = 0.f;
#pragma unroll
        for (int q = 0; q < 8; q++) {
            ax += p[q] * bf2f(uu[q].x);
            ay += p[q] * bf2f(uu[q].y);
            az += p[q] * bf2f(uu[q].z);
            aw += p[q] * bf2f(uu[q].w);
        }
        acc.x = acc.x * sc + ax;
        acc.y = acc.y * sc + ay;
        acc.z = acc.z * sc + az;
        acc.w = acc.w * sc + aw;
        m = mn;
    }
    for (; j + 3 < je; j += 4) {
        int s0 = csr_src[j], s1 = csr_src[j + 1], s2 = csr_src[j + 2], s3 = csr_src[j + 3];
        ushort4 u0 = *reinterpret_cast<const ushort4*>(&feat16[(size_t)s0 * 256 + lane * 4]);
        ushort4 u1 = *reinterpret_cast<const ushort4*>(&feat16[(size_t)s1 * 256 + lane * 4]);
        ushort4 u2 = *reinterpret_cast<const ushort4*>(&feat16[(size_t)s2 * 256 + lane * 4]);
        ushort4 u3 = *reinterpret_cast<const ushort4*>(&feat16[(size_t)s3 * 256 + lane * 4]);
        float v0 = lrelu(el[s0 * 4 + h] + er_nh);
        float v1 = lrelu(el[s1 * 4 + h] + er_nh);
        float v2 = lrelu(el[s2 * 4 + h] + er_nh);
        float v3 = lrelu(el[s3 * 4 + h] + er_nh);
        float mx = fmaxf(fmaxf(v0, v1), fmaxf(v2, v3));
        float mn = fmaxf(m, mx);
        float sc = __expf(m - mn);
        float p0 = __expf(v0 - mn);
        float p1 = __expf(v1 - mn);
        float p2 = __expf(v2 - mn);
        float p3 = __expf(v3 - mn);
        ssum = ssum * sc + ((p0 + p1) + (p2 + p3));
        acc.x = acc.x * sc + (p0 * bf2f(u0.x) + p1 * bf2f(u1.x)) + (p2 * bf2f(u2.x) + p3 * bf2f(u3.x));
        acc.y = acc.y * sc + (p0 * bf2f(u0.y) + p1 * bf2f(u1.y)) + (p2 * bf2f(u2.y) + p3 * bf2f(u3.y));
        acc.z = acc.z * sc + (p0 * bf2f(u0.z) + p1 * bf2f(u1.z)) + (p2 * bf2f(u2.z) + p3 * bf2f(u3.z));
        acc.w = acc.w * sc + (p0 * bf2f(u0.w) + p1 * bf2f(u1.w)) + (p2 * bf2f(u2.w) + p3 * bf2f(u3.w));
        m = mn;
    }
    for (; j < je; j++) {
        int s = csr_src[j];
        ushort4 u = *reinterpret_cast<const ushort4*>(&feat16[(size_t)s * 256 + lane * 4]);
        float val = lrelu(el[s * 4 + h] + er_nh);
        float mn = fmaxf(m, val);
        float sc = __expf(m - mn);
        float p = __expf(val - mn);
        ssum = ssum * sc + p;
        acc.x = acc.x * sc + p * bf2f(u.x);
        acc.y = acc.y * sc + p * bf2f(u.y);
        acc.z = acc.z * sc + p * bf2f(u.z);
        acc.w = acc.w * sc + p * bf2f(u.w);
        m = mn;
    }
    float inv = 1.f / fmaxf(ssum, 1e-9f);
    // bias index: h*64 + (lane&15)*4 + i == lane*4 + i
    float4 res;
    res.x = acc.x * inv + bias[lane * 4 + 0];
    res.y = acc.y * inv + bias[lane * 4 + 1];
    res.z = acc.z * inv + bias[lane * 4 + 2];
    res.w = acc.w * inv + bias[lane * 4 + 3];
    if (LAYER == 1) {
        res.x = res.x > 0.f ? res.x : __expf(res.x) - 1.f;
        res.y = res.y > 0.f ? res.y : __expf(res.y) - 1.f;
        res.z = res.z > 0.f ? res.z : __expf(res.z) - 1.f;
        res.w = res.w > 0.f ? res.w : __expf(res.w) - 1.f;
        ushort4 hz, lz;
        hz.x = f2bf(res.x); lz.x = f2bf(res.x - bf2f(hz.x));
        hz.y = f2bf(res.y); lz.y = f2bf(res.y - bf2f(hz.y));
        hz.z = f2bf(res.z); lz.z = f2bf(res.z - bf2f(hz.z));
        hz.w = f2bf(res.w); lz.w = f2bf(res.w - bf2f(hz.w));
        *reinterpret_cast<ushort4*>(&out_hi[(size_t)n * 256 + lane * 4]) = hz;
        *reinterpret_cast<ushort4*>(&out_lo[(size_t)n * 256 + lane * 4]) = lz;
    } else {
        // mean over heads: feature f held by lanes {f>>2, +16, +32, +48}
#pragma unroll
        for (int mask = 16; mask <= 32; mask <<= 1) {
            res.x += __shfl_xor(res.x, mask, 64);
            res.y += __shfl_xor(res.y, mask, 64);
            res.z += __shfl_xor(res.z, mask, 64);
            res.w += __shfl_xor(res.w, mask, 64);
        }
        if (lane < 16) {
            float4 o = make_float4(res.x * 0.25f, res.y * 0.25f, res.z * 0.25f, res.w * 0.25f);
            *reinterpret_cast<float4*>(&outf[(size_t)n * 64 + lane * 4]) = o;
        }
    }
}

// ---------------- launch ----------------

extern "C" void kernel_launch(void* const* d_in, const int* in_sizes, int n_in,
                              void* d_out, int out_size, void* d_ws, size_t ws_size,
                              hipStream_t stream) {
    const float* features = (const float*)d_in[0];
    const int*   src      = (const int*)d_in[1];
    const int*   dst      = (const int*)d_in[2];
    const float* W1       = (const float*)d_in[3];
    const float* al1      = (const float*)d_in[4];
    const float* ar1      = (const float*)d_in[5];
    const float* b1       = (const float*)d_in[6];
    const float* W2       = (const float*)d_in[7];
    const float* al2      = (const float*)d_in[8];
    const float* ar2      = (const float*)d_in[9];
    const float* b2       = (const float*)d_in[10];
    float* out = (float*)d_out;

    char* ws = (char*)d_ws;
    unsigned short* feat16  = (unsigned short*)(ws);             // 25,600,000 B [50000x256]
    unsigned short* h1_hi   = (unsigned short*)(ws + 25600000);  // 25,600,000 B
    unsigned short* h1_lo   = (unsigned short*)(ws + 51200000);  // 25,600,000 B
    unsigned short* Bt1_hi  = (unsigned short*)(ws + 76800000);  //     65,536 B
    unsigned short* Bt1_lo  = (unsigned short*)(ws + 76865536);  //     65,536 B
    unsigned short* Bt2_hi  = (unsigned short*)(ws + 76931072);  //    131,072 B
    unsigned short* Bt2_lo  = (unsigned short*)(ws + 77062144);  //    131,072 B
    unsigned short* E1C_hi  = (unsigned short*)(ws + 77193216);  //      2,048 B [4][2][128]
    unsigned short* E1C_lo  = (unsigned short*)(ws + 77195264);  //      2,048 B
    unsigned short* E2C_hi  = (unsigned short*)(ws + 77197312);  //      4,096 B [4][2][256]
    unsigned short* E2C_lo  = (unsigned short*)(ws + 77201408);  //      4,096 B
    float*          el      = (float*)(ws + 77205504);           //    800,000 B
    float*          er      = (float*)(ws + 78005504);           //    800,000 B
    int*            row_off = (int*)  (ws + 78805504);           //    200,064 B
    int*            cur     = (int*)  (ws + 79005568);           //    200,000 B
    int*            part    = (int*)  (ws + 79205568);           //      1,024 B
    int*            csr     = (int*)  (ws + 79206592);           //  3,200,000 B (end ~82.4 MB)

    // --- CSR build (graph shared by both layers) ---
    zero_int<<<(N_NODES + 255) / 256, 256, 0, stream>>>(cur, N_NODES);
    hist_kernel<<<(N_EDGES + 255) / 256, 256, 0, stream>>>(dst, cur);
    int nb = (N_NODES + 255) / 256;   // 196
    scan_part<<<nb, 256, 0, stream>>>(cur, row_off, part, N_NODES);
    scan_carry<<<1, 256, 0, stream>>>(part, nb);
    scan_add<<<(N_NODES + 255) / 256, 256, 0, stream>>>(row_off, part, cur, N_NODES);
    scatter_kernel<<<(N_EDGES + 255) / 256, 256, 0, stream>>>(src, dst, cur, csr);

    // --- weight prep ---
    split_wt<IN_DIM><<<IN_DIM, 256, 0, stream>>>(W1, Bt1_hi, Bt1_lo);
    split_wt<256><<<256, 256, 0, stream>>>(W2, Bt2_hi, Bt2_lo);
    wlr_kernel<IN_DIM><<<1, IN_DIM, 0, stream>>>(W1, al1, ar1, E1C_hi, E1C_lo);
    wlr_kernel<256><<<1, 256, 0, stream>>>(W2, al2, ar2, E2C_hi, E2C_lo);

    int gemm_blocks = (N_NODES + 127) / 128;   // 391

    // --- layer 1 (A = fp32 features, split fused into staging) ---
    mfma_gemm<IN_DIM, true><<<gemm_blocks, 512, 0, stream>>>(
        features, nullptr, Bt1_hi, Bt1_lo, E1C_hi, E1C_lo, feat16, el, er, N_NODES);
    agg_kernel<1><<<12500, 256, 0, stream>>>(feat16, el, er, row_off, csr, b1, h1_hi, h1_lo, nullptr);

    // --- layer 2 (A = h1 hi/lo bf16) ---
    mfma_gemm<256, false><<<gemm_blocks, 512, 0, stream>>>(
        h1_hi, h1_lo, Bt2_hi, Bt2_lo, E2C_hi, E2C_lo, feat16, el, er, N_NODES);
    agg_kernel<2><<<12500, 256, 0, stream>>>(feat16, el, er, row_off, csr, b2, nullptr, nullptr, out);
}